// Round 6
// baseline (226.034 us; speedup 1.0000x reference)
//
#include <hip/hip_runtime.h>
#include <cstdint>
#include <cstddef>

#define Bn 8192
#define Dn 1024
#define Hn 1024
#define En 8
#define MT 128                     // expert padding quantum / m-tile
#define MTILES (PERM_N / MT)       // 72
#define PERM_N (Bn + En * MT)      // 9216

// prep_k block ranges
#define NXB 4096                   // x-convert blocks
#define NWB 2048                   // W1-transpose blocks
#define NZB 32                     // logit-zero blocks
#define XB0 1
#define WB0 (XB0 + NXB)
#define ZB0 (WB0 + NWB)
#define TOTB (ZB0 + NZB)           // 6177

typedef unsigned short u16;
typedef __bf16 bf16x8 __attribute__((ext_vector_type(8)));
typedef float f32x4 __attribute__((ext_vector_type(4)));
typedef unsigned short ushort8 __attribute__((ext_vector_type(8)));

// ---------- helpers ----------
__device__ __forceinline__ u16 f2bf(float f) {
  unsigned int u = __float_as_uint(f);
  unsigned int r = u + 0x7fffu + ((u >> 16) & 1u);   // RNE
  return (u16)(r >> 16);
}

__device__ __forceinline__ void gld16(const void* g, void* l) {
  __builtin_amdgcn_global_load_lds(
      (const __attribute__((address_space(1))) void*)g,
      (__attribute__((address_space(3))) void*)l, 16, 0, 0);
}

// wait for own vmcnt<=N (lgkm/exp untouched), then workgroup barrier.
// imm: vmcnt[3:0] | expcnt[6:4] | lgkmcnt[11:8]
#define PIPE_BARRIER_VM4() do {                    \
    asm volatile("" ::: "memory");                 \
    __builtin_amdgcn_s_waitcnt(0x0F74);            \
    __builtin_amdgcn_s_barrier();                  \
    asm volatile("" ::: "memory");                 \
  } while (0)
#define PIPE_BARRIER_VM0() do {                    \
    asm volatile("" ::: "memory");                 \
    __builtin_amdgcn_s_waitcnt(0x0F70);            \
    __builtin_amdgcn_s_barrier();                  \
    asm volatile("" ::: "memory");                 \
  } while (0)

// ---------- prep: routing + x->bf16 + W1 transpose + zero, ONE dispatch ----------
__global__ __launch_bounds__(256) void prep_k(
    const float* __restrict__ x, const int* __restrict__ sidx,
    const float* __restrict__ W1,
    u16* __restrict__ xb, u16* __restrict__ w1t,
    int* __restrict__ off, int* __restrict__ perm, int* __restrict__ done,
    float* __restrict__ out) {
  int bid = blockIdx.x;
  int t = threadIdx.x;

  if (bid == 0) {
    // ---- routing (single block, 256 threads) ----
    __shared__ int hist[4][En];
    __shared__ int base[4][En];
    __shared__ int eoff[En + 1];
    int wv = t >> 6;
    if (t < 4 * En) ((int*)hist)[t] = 0;
    if (t < MTILES) done[t] = 0;
#pragma unroll
    for (int i = 0; i < PERM_N / 256; i++) perm[t + i * 256] = -1;  // pad fill
    __syncthreads();
    int e32[32], r32[32];
#pragma unroll
    for (int i = 0; i < 32; i++) {
      int e = sidx[t + i * 256];
      e32[i] = e;
      r32[i] = atomicAdd(&hist[wv][e], 1);
    }
    __syncthreads();
    if (t < En) {
      int s = 0;
      for (int w = 0; w < 4; w++) { base[w][t] = s; s += hist[w][t]; }
      hist[0][t] = s;
    }
    __syncthreads();
    if (t == 0) {
      int o = 0;
      for (int e = 0; e < En; e++) {
        eoff[e] = o; off[e] = o;
        o += (hist[0][e] + MT - 1) & ~(MT - 1);
      }
      eoff[En] = o; off[En] = o;
    }
    __syncthreads();
#pragma unroll
    for (int i = 0; i < 32; i++) {
      int e = e32[i];
      perm[eoff[e] + base[wv][e] + r32[i]] = t + i * 256;
    }
  } else if (bid < WB0) {
    // ---- x fp32 -> bf16, natural order ----
    size_t idx = ((size_t)(bid - XB0) * 256 + t) * 8;
    const float* src = x + idx;
    float4 a = *(const float4*)src;
    float4 b = *(const float4*)(src + 4);
    ushort8 o;
    o[0] = f2bf(a.x); o[1] = f2bf(a.y); o[2] = f2bf(a.z); o[3] = f2bf(a.w);
    o[4] = f2bf(b.x); o[5] = f2bf(b.y); o[6] = f2bf(b.z); o[7] = f2bf(b.w);
    *(ushort8*)(xb + idx) = o;
  } else if (bid < ZB0) {
    // ---- W1 [E][D][H] fp32 -> W1t [E][H][D] bf16, 64x64 LDS transpose ----
    __shared__ float tile[64][65];
    int wb = bid - WB0;
    int e = wb >> 8;
    int k0 = ((wb >> 4) & 15) * 64;   // D
    int n0 = (wb & 15) * 64;          // H
    int c4 = (t & 15) * 4;
    int r0 = t >> 4;                  // 0..15
    const float* src = W1 + ((size_t)e << 20) + (size_t)k0 * Hn + n0;
#pragma unroll
    for (int i = 0; i < 4; i++) {
      int r = r0 + i * 16;
      float4 v = *(const float4*)(src + (size_t)r * Hn + c4);
      tile[r][c4 + 0] = v.x; tile[r][c4 + 1] = v.y;
      tile[r][c4 + 2] = v.z; tile[r][c4 + 3] = v.w;
    }
    __syncthreads();
    u16* dst = w1t + ((size_t)e << 20) + (size_t)n0 * Dn + k0;
#pragma unroll
    for (int i = 0; i < 4; i++) {
      int h = r0 + i * 16;
      ushort4 o;
      o.x = f2bf(tile[c4 + 0][h]);
      o.y = f2bf(tile[c4 + 1][h]);
      o.z = f2bf(tile[c4 + 2][h]);
      o.w = f2bf(tile[c4 + 3][h]);
      *(ushort4*)(dst + (size_t)h * Dn + c4) = o;
    }
  } else {
    // ---- zero logit accumulators out[0 .. Bn*4) ----
    size_t idx = ((size_t)(bid - ZB0) * 256 + t) * 4;
    *(float4*)(out + idx) = make_float4(0.f, 0.f, 0.f, 0.f);
  }
}

// ---------- grouped GEMM: 128x128, 3-stage vmcnt(4) pipeline, gather-A,
// ---------- fused layer-2 atomics + last-block ordinal probs ----------
__global__ __launch_bounds__(256) void gemm_k(
    const u16* __restrict__ xb, const u16* __restrict__ w1t,
    const float* __restrict__ b1, const float* __restrict__ w2,
    const float* __restrict__ b2,
    const int* __restrict__ off, const int* __restrict__ perm,
    int* __restrict__ done, float* __restrict__ out) {
  __shared__ u16 As[3][4096];   // 3 stages x 128 rows x 32 k (8 KB each)
  __shared__ u16 Bs[3][4096];
  __shared__ int sOld;

  int n0 = blockIdx.x * 128;            // x = n-tile: pins n-slice to one XCD
  int tb = blockIdx.y;
  int row0 = tb * MT;
  if (row0 >= off[En]) return;          // dead (all-pad) tile
  int e = 0;
  while (row0 >= off[e + 1]) e++;

  int tid = threadIdx.x;
  int lane = tid & 63, w = tid >> 6;
  int wm = w >> 1, wn = w & 1;

  // staging: HW puts lane L at LDS base + L*16B -> (row L>>2, slot L&3).
  // source chunk q = slot ^ swz(row) implements the xor swizzle.
  int srow = lane >> 2;
  int slot = lane & 3;
  int scol = (slot ^ ((srow >> 1) & 3)) * 8;
  const u16* aG[2]; const u16* bG[2];
  int lOff[2];
#pragma unroll
  for (int j = 0; j < 2; j++) {
    int rl = 32 * w + 16 * j + srow;
    int tok = perm[row0 + rl];
    if (tok < 0) tok = 0;               // pad row: any valid row (result discarded)
    aG[j] = xb + ((size_t)tok << 10) + scol;
    bG[j] = w1t + ((size_t)e << 20) + (size_t)(n0 + rl) * Dn + scol;
    lOff[j] = (32 * w + 16 * j) * 32;   // wave-uniform LDS base (elements)
  }

  f32x4 acc[4][4];
#pragma unroll
  for (int i = 0; i < 4; i++)
#pragma unroll
    for (int j = 0; j < 4; j++)
      acc[i][j] = (f32x4){0.f, 0.f, 0.f, 0.f};

  int fr = lane & 15;
  int qf = lane >> 4;
  int qs = (qf ^ ((fr >> 1) & 3)) * 8;
  int offA[4], offB[4];
#pragma unroll
  for (int i = 0; i < 4; i++)
    offA[i] = (wm * 64 + i * 16 + fr) * 32 + qs;
#pragma unroll
  for (int j = 0; j < 4; j++)
    offB[j] = (wn * 64 + j * 16 + fr) * 32 + qs;

  // prologue: stages 0,1 in flight
#pragma unroll
  for (int it = 0; it < 2; it++) {
    int ko = it * 32;
    gld16(aG[0] + ko, (u16*)As[it] + lOff[0]);
    gld16(aG[1] + ko, (u16*)As[it] + lOff[1]);
    gld16(bG[0] + ko, (u16*)Bs[it] + lOff[0]);
    gld16(bG[1] + ko, (u16*)Bs[it] + lOff[1]);
  }

#pragma unroll
  for (int i = 0; i < 31; i++) {
    PIPE_BARRIER_VM4();                 // stage-i done; stage-(i+1) in flight
    if (i + 2 < 32) {
      int s = (i + 2) % 3;
      int ko = (i + 2) * 32;
      gld16(aG[0] + ko, (u16*)As[s] + lOff[0]);
      gld16(aG[1] + ko, (u16*)As[s] + lOff[1]);
      gld16(bG[0] + ko, (u16*)Bs[s] + lOff[0]);
      gld16(bG[1] + ko, (u16*)Bs[s] + lOff[1]);
    }
    const u16* Ab = (const u16*)As[i % 3];
    const u16* Bb = (const u16*)Bs[i % 3];
    bf16x8 af[4], bfr[4];
#pragma unroll
    for (int ii = 0; ii < 4; ii++) af[ii] = *(const bf16x8*)(Ab + offA[ii]);
#pragma unroll
    for (int jj = 0; jj < 4; jj++) bfr[jj] = *(const bf16x8*)(Bb + offB[jj]);
#pragma unroll
    for (int ii = 0; ii < 4; ii++)
#pragma unroll
      for (int jj = 0; jj < 4; jj++)
        acc[ii][jj] = __builtin_amdgcn_mfma_f32_16x16x32_bf16(af[ii], bfr[jj], acc[ii][jj], 0, 0, 0);
  }
  {                                     // peeled last iteration (full drain)
    PIPE_BARRIER_VM0();
    const u16* Ab = (const u16*)As[31 % 3];
    const u16* Bb = (const u16*)Bs[31 % 3];
    bf16x8 af[4], bfr[4];
#pragma unroll
    for (int ii = 0; ii < 4; ii++) af[ii] = *(const bf16x8*)(Ab + offA[ii]);
#pragma unroll
    for (int jj = 0; jj < 4; jj++) bfr[jj] = *(const bf16x8*)(Bb + offB[jj]);
#pragma unroll
    for (int ii = 0; ii < 4; ii++)
#pragma unroll
      for (int jj = 0; jj < 4; jj++)
        acc[ii][jj] = __builtin_amdgcn_mfma_f32_16x16x32_bf16(af[ii], bfr[jj], acc[ii][jj], 0, 0, 0);
  }

  // epilogue: h = relu(acc + b1); logits += h . W2[e][col][0..3] via atomics
  float4 w2v[4]; float b1v[4];
#pragma unroll
  for (int j = 0; j < 4; j++) {
    int col = n0 + wn * 64 + j * 16 + fr;
    w2v[j] = *(const float4*)(w2 + ((size_t)e * Hn + col) * 4);
    b1v[j] = b1[(size_t)e * Hn + col];
  }
#pragma unroll
  for (int i = 0; i < 4; i++) {
    int rbase = wm * 64 + i * 16 + qf * 4;
#pragma unroll
    for (int r = 0; r < 4; r++) {
      float s0 = 0.f, s1 = 0.f, s2 = 0.f, s3 = 0.f;
#pragma unroll
      for (int j = 0; j < 4; j++) {
        float h = acc[i][j][r] + b1v[j];
        h = fmaxf(h, 0.f);
        s0 = fmaf(h, w2v[j].x, s0);
        s1 = fmaf(h, w2v[j].y, s1);
        s2 = fmaf(h, w2v[j].z, s2);
        s3 = fmaf(h, w2v[j].w, s3);
      }
#pragma unroll
      for (int m = 1; m < 16; m <<= 1) {
        s0 += __shfl_xor(s0, m);
        s1 += __shfl_xor(s1, m);
        s2 += __shfl_xor(s2, m);
        s3 += __shfl_xor(s3, m);
      }
      if (fr == 0) {
        int tok = perm[row0 + rbase + r];
        if (tok >= 0) {
          float* o = out + (size_t)tok * 4;
          atomicAdd(o + 0, s0);
          atomicAdd(o + 1, s1);
          atomicAdd(o + 2, s2);
          atomicAdd(o + 3, s3);
        }
      }
    }
  }

  // last-arriving block of this m-tile computes ordinal probs for its 128 rows
  __syncthreads();                       // all waves' atomics issued & drained
  if (tid == 0) {
    __threadfence();
    sOld = atomicAdd(&done[tb], 1);
  }
  __syncthreads();
  if (sOld == 7) {
    __threadfence();
    if (tid < MT) {
      int tok = perm[row0 + tid];
      if (tok >= 0) {
        float l0 = out[tok * 4 + 0] + b2[e * 4 + 0];
        float l1 = out[tok * 4 + 1] + b2[e * 4 + 1];
        float l2 = out[tok * 4 + 2] + b2[e * 4 + 2];
        float l3 = out[tok * 4 + 3] + b2[e * 4 + 3];
        out[tok * 4 + 0] = l0; out[tok * 4 + 1] = l1;
        out[tok * 4 + 2] = l2; out[tok * 4 + 3] = l3;
        float q0 = 1.f / (1.f + expf(-l0));
        float q1 = 1.f / (1.f + expf(-l1));
        float q2 = 1.f / (1.f + expf(-l2));
        float q3 = 1.f / (1.f + expf(-l3));
        const float eps = 1e-8f;
        float p0 = fmaxf(1.f - q0, eps);
        float p1 = fmaxf(q0 - q1, eps);
        float p2 = fmaxf(q1 - q2, eps);
        float p3 = fmaxf(q2 - q3, eps);
        float p4 = fmaxf(q3, eps);
        float s = p0 + p1 + p2 + p3 + p4;
        float inv = 1.f / fmaxf(s, eps);
        float* pr = out + (size_t)Bn * 4 + (size_t)tok * 5;
        pr[0] = p0 * inv; pr[1] = p1 * inv; pr[2] = p2 * inv;
        pr[3] = p3 * inv; pr[4] = p4 * inv;
      }
    }
  }
}

// ---------- launch ----------
extern "C" void kernel_launch(void* const* d_in, const int* in_sizes, int n_in,
                              void* d_out, int out_size, void* d_ws, size_t ws_size,
                              hipStream_t stream) {
  const float* x  = (const float*)d_in[0];
  const int* sidx = (const int*)d_in[1];
  const float* W1 = (const float*)d_in[2];
  const float* b1 = (const float*)d_in[3];
  const float* W2 = (const float*)d_in[4];
  const float* b2 = (const float*)d_in[5];
  float* out = (float*)d_out;

  uint8_t* w = (uint8_t*)d_ws;
  int* off  = (int*)(w + 64);     // 9 ints
  int* done = (int*)(w + 128);    // 72 ints
  int* perm = (int*)(w + 512);    // 9216 ints
  u16* xb   = (u16*)(w + 40960);                     // 16,777,216 B
  u16* w1t  = (u16*)(w + 40960 + 16777216);          // 16,777,216 B

  prep_k<<<TOTB, 256, 0, stream>>>(x, sidx, W1, xb, w1t, off, perm, done, out);
  gemm_k<<<dim3(Hn / 128, MTILES), 256, 0, stream>>>(xb, w1t, b1, W2, b2,
                                                     off, perm, done, out);
}

// Round 7
// 171.620 us; speedup vs baseline: 1.3171x; 1.3171x over previous
//
#include <hip/hip_runtime.h>
#include <cstdint>
#include <cstddef>

#define Bn 8192
#define Dn 1024
#define Hn 1024
#define En 8
#define MT 128                     // expert padding quantum / m-tile
#define MTILES (PERM_N / MT)       // 72
#define PERM_N (Bn + En * MT)      // 9216
#define NB 16                      // 64-col partial chunks per row

typedef unsigned short u16;
typedef __bf16 bf16x8 __attribute__((ext_vector_type(8)));
typedef float f32x4 __attribute__((ext_vector_type(4)));
typedef unsigned short ushort8 __attribute__((ext_vector_type(8)));

// ---------- helpers ----------
__device__ __forceinline__ u16 f2bf(float f) {
  unsigned int u = __float_as_uint(f);
  unsigned int r = u + 0x7fffu + ((u >> 16) & 1u);   // RNE
  return (u16)(r >> 16);
}

__device__ __forceinline__ void gld16(const void* g, void* l) {
  __builtin_amdgcn_global_load_lds(
      (const __attribute__((address_space(1))) void*)g,
      (__attribute__((address_space(3))) void*)l, 16, 0, 0);
}

// wait for own vmcnt<=N (lgkm/exp untouched), then workgroup barrier.
// imm: vmcnt[3:0] | expcnt[6:4] | lgkmcnt[11:8]
#define PIPE_WAIT_BARRIER(imm) do {                \
    asm volatile("" ::: "memory");                 \
    __builtin_amdgcn_s_waitcnt(imm);               \
    __builtin_amdgcn_s_barrier();                  \
    asm volatile("" ::: "memory");                 \
  } while (0)

// ---------- D1: expert counts (blocks 0..7) + W1 transpose (blocks 8..2055) ----------
__global__ __launch_bounds__(256) void prep_k(const int* __restrict__ sidx,
                                              const float* __restrict__ W1,
                                              u16* __restrict__ w1t,
                                              int* __restrict__ cnt) {
  int bid = blockIdx.x;
  int t = threadIdx.x;
  if (bid < 8) {
    // ---- count: 1024 tokens per block, per-wave LDS hist, 8 global atomics ----
    __shared__ int hist[4][En];
    int wv = t >> 6;
    if (t < 4 * En) ((int*)hist)[t] = 0;
    __syncthreads();
#pragma unroll
    for (int i = 0; i < 4; i++) {
      int e = sidx[bid * 1024 + t + i * 256];
      atomicAdd(&hist[wv][e], 1);
    }
    __syncthreads();
    if (t < En) {
      int s = hist[0][t] + hist[1][t] + hist[2][t] + hist[3][t];
      atomicAdd(&cnt[t], s);
    }
  } else {
    // ---- W1 [E][D][H] fp32 -> W1t [E][H][D] bf16, 64x64 LDS transpose ----
    __shared__ float tile[64][65];
    int wb = bid - 8;
    int e = wb >> 8;
    int k0 = ((wb >> 4) & 15) * 64;   // D
    int n0 = (wb & 15) * 64;          // H
    int c4 = (t & 15) * 4;
    int r0 = t >> 4;                  // 0..15
    const float* src = W1 + ((size_t)e << 20) + (size_t)k0 * Hn + n0;
#pragma unroll
    for (int i = 0; i < 4; i++) {
      int r = r0 + i * 16;
      float4 v = *(const float4*)(src + (size_t)r * Hn + c4);
      tile[r][c4 + 0] = v.x; tile[r][c4 + 1] = v.y;
      tile[r][c4 + 2] = v.z; tile[r][c4 + 3] = v.w;
    }
    __syncthreads();
    u16* dst = w1t + ((size_t)e << 20) + (size_t)n0 * Dn + k0;
#pragma unroll
    for (int i = 0; i < 4; i++) {
      int h = r0 + i * 16;
      ushort4 o;
      o.x = f2bf(tile[c4 + 0][h]);
      o.y = f2bf(tile[c4 + 1][h]);
      o.z = f2bf(tile[c4 + 2][h]);
      o.w = f2bf(tile[c4 + 3][h]);
      *(ushort4*)(dst + (size_t)h * Dn + c4) = o;
    }
  }
}

// ---------- D2: parallel rank/scatter (blocks 0..31) + pad fill (32..39) ----------
__global__ __launch_bounds__(256) void rank_k(const int* __restrict__ sidx,
                                              const int* __restrict__ cnt,
                                              int* __restrict__ gcur,
                                              int* __restrict__ off,
                                              int* __restrict__ perm) {
  int b = blockIdx.x, t = threadIdx.x;
  // padded offsets from global counts (8 scalar loads, every block)
  int offl[En + 1];
  int o = 0;
#pragma unroll
  for (int e = 0; e < En; e++) { offl[e] = o; o += (cnt[e] + MT - 1) & ~(MT - 1); }
  offl[En] = o;

  if (b < 32) {
    __shared__ int hist[4][En];
    __shared__ int wbase[4][En];
    __shared__ int bbase[En];
    int wv = t >> 6;
    if (t < 4 * En) ((int*)hist)[t] = 0;
    __syncthreads();
    int tok = b * 256 + t;
    int e = sidx[tok];
    int r = atomicAdd(&hist[wv][e], 1);
    __syncthreads();
    if (t < En) {
      int s = 0;
#pragma unroll
      for (int w = 0; w < 4; w++) { wbase[w][t] = s; s += hist[w][t]; }
      bbase[t] = atomicAdd(&gcur[t], s);   // global rank base for this block
    }
    __syncthreads();
    int eo = offl[0];
    // index offl dynamically via small select chain (avoid scratch)
    int sel = e;
    eo = (sel == 0) ? offl[0] : (sel == 1) ? offl[1] : (sel == 2) ? offl[2] :
         (sel == 3) ? offl[3] : (sel == 4) ? offl[4] : (sel == 5) ? offl[5] :
         (sel == 6) ? offl[6] : offl[7];
    int dest = eo + bbase[e] + wbase[wv][e] + r;
    perm[dest] = tok;
  } else {
    int e = b - 32;
    int start = 0, end = 0, o2 = 0;
#pragma unroll
    for (int i = 0; i < En; i++) {
      int pad = (cnt[i] + MT - 1) & ~(MT - 1);
      if (i == e) { start = o2 + cnt[i]; end = o2 + pad; }
      o2 += pad;
    }
    for (int p = start + t; p < end; p += 256) perm[p] = -1;   // pad rows
    if (e == 0 && t == 0) {
#pragma unroll
      for (int i = 0; i <= En; i++) off[i] = offl[i];
    }
  }
}

// ---------- D3: gather+convert, one row per block ----------
__global__ __launch_bounds__(256) void gather_k(const float* __restrict__ x,
                                                const int* __restrict__ perm,
                                                u16* __restrict__ xbp) {
  int p = blockIdx.x;
  int t = threadIdx.x;
  int tok = perm[p];
  u16* dst = xbp + ((size_t)p << 10) + t * 4;
  if (tok < 0) {
    *(ushort4*)dst = (ushort4){0, 0, 0, 0};
  } else {
    float4 v = *(const float4*)(x + ((size_t)tok << 10) + t * 4);
    ushort4 o;
    o.x = f2bf(v.x); o.y = f2bf(v.y); o.z = f2bf(v.z); o.w = f2bf(v.w);
    *(ushort4*)dst = o;
  }
}

// ---------- D4: grouped GEMM, 128x128, 4-stage dist-3 vmcnt(8) pipeline ----------
__global__ __launch_bounds__(256) void gemm_k(
    const u16* __restrict__ xbp, const u16* __restrict__ w1t,
    const float* __restrict__ b1, const float* __restrict__ w2,
    const int* __restrict__ off, float* __restrict__ partials) {
  __shared__ u16 As[4][4096];   // 4 stages x 128 rows x 32 k (8 KB each)
  __shared__ u16 Bs[4][4096];

  int n0 = blockIdx.x * 128;            // x = n-tile: pins n-slice to one XCD
  int row0 = blockIdx.y * MT;
  if (row0 >= off[En]) return;          // dead (all-pad) tile
  int e = 0;
  while (row0 >= off[e + 1]) e++;

  int tid = threadIdx.x;
  int lane = tid & 63, w = tid >> 6;
  int wm = w >> 1, wn = w & 1;

  // staging: HW puts lane L at LDS base + L*16B -> (row L>>2, slot L&3).
  // source chunk q = slot ^ swz(row) implements the xor swizzle.
  int srow = lane >> 2;
  int slot = lane & 3;
  int scol = (slot ^ ((srow >> 1) & 3)) * 8;
  const u16* aG[2]; const u16* bG[2];
  int lOff[2];
#pragma unroll
  for (int j = 0; j < 2; j++) {
    int rl = 32 * w + 16 * j + srow;
    aG[j] = xbp + (size_t)(row0 + rl) * Dn + scol;
    bG[j] = w1t + ((size_t)e << 20) + (size_t)(n0 + rl) * Dn + scol;
    lOff[j] = (32 * w + 16 * j) * 32;   // wave-uniform LDS base (elements)
  }

  f32x4 acc[4][4];
#pragma unroll
  for (int i = 0; i < 4; i++)
#pragma unroll
    for (int j = 0; j < 4; j++)
      acc[i][j] = (f32x4){0.f, 0.f, 0.f, 0.f};

  int fr = lane & 15;
  int qf = lane >> 4;
  int qs = (qf ^ ((fr >> 1) & 3)) * 8;
  int offA[4], offB[4];
#pragma unroll
  for (int i = 0; i < 4; i++)
    offA[i] = (wm * 64 + i * 16 + fr) * 32 + qs;
#pragma unroll
  for (int j = 0; j < 4; j++)
    offB[j] = (wn * 64 + j * 16 + fr) * 32 + qs;

  // prologue: stages 0,1,2 in flight (12 loads/thread)
#pragma unroll
  for (int it = 0; it < 3; it++) {
    int ko = it * 32;
    gld16(aG[0] + ko, (u16*)As[it] + lOff[0]);
    gld16(aG[1] + ko, (u16*)As[it] + lOff[1]);
    gld16(bG[0] + ko, (u16*)Bs[it] + lOff[0]);
    gld16(bG[1] + ko, (u16*)Bs[it] + lOff[1]);
  }

#pragma unroll
  for (int i = 0; i < 32; i++) {
    // ensure stage i landed; keep later stages' loads in flight
    if (i <= 29)      PIPE_WAIT_BARRIER(0x0F78);   // vmcnt(8)
    else if (i == 30) PIPE_WAIT_BARRIER(0x0F74);   // vmcnt(4)
    else              PIPE_WAIT_BARRIER(0x0F70);   // vmcnt(0)
    if (i + 3 < 32) {
      int s = (i + 3) & 3;
      int ko = (i + 3) * 32;
      gld16(aG[0] + ko, (u16*)As[s] + lOff[0]);
      gld16(aG[1] + ko, (u16*)As[s] + lOff[1]);
      gld16(bG[0] + ko, (u16*)Bs[s] + lOff[0]);
      gld16(bG[1] + ko, (u16*)Bs[s] + lOff[1]);
    }
    const u16* Ab = (const u16*)As[i & 3];
    const u16* Bb = (const u16*)Bs[i & 3];
    bf16x8 af[4], bfr[4];
#pragma unroll
    for (int ii = 0; ii < 4; ii++) af[ii] = *(const bf16x8*)(Ab + offA[ii]);
#pragma unroll
    for (int jj = 0; jj < 4; jj++) bfr[jj] = *(const bf16x8*)(Bb + offB[jj]);
#pragma unroll
    for (int ii = 0; ii < 4; ii++)
#pragma unroll
      for (int jj = 0; jj < 4; jj++)
        acc[ii][jj] = __builtin_amdgcn_mfma_f32_16x16x32_bf16(af[ii], bfr[jj], acc[ii][jj], 0, 0, 0);
  }

  // epilogue: h = relu(acc + b1); partial = h . W2[e][col][0..3]; float4 per row/chunk
  float4 w2v[4]; float b1v[4];
#pragma unroll
  for (int j = 0; j < 4; j++) {
    int col = n0 + wn * 64 + j * 16 + fr;
    w2v[j] = *(const float4*)(w2 + ((size_t)e * Hn + col) * 4);
    b1v[j] = b1[(size_t)e * Hn + col];
  }
  int chunk = blockIdx.x * 2 + wn;      // 64-col chunk 0..15
#pragma unroll
  for (int i = 0; i < 4; i++) {
    int rbase = wm * 64 + i * 16 + qf * 4;
#pragma unroll
    for (int r = 0; r < 4; r++) {
      float s0 = 0.f, s1 = 0.f, s2 = 0.f, s3 = 0.f;
#pragma unroll
      for (int j = 0; j < 4; j++) {
        float h = acc[i][j][r] + b1v[j];
        h = fmaxf(h, 0.f);
        s0 = fmaf(h, w2v[j].x, s0);
        s1 = fmaf(h, w2v[j].y, s1);
        s2 = fmaf(h, w2v[j].z, s2);
        s3 = fmaf(h, w2v[j].w, s3);
      }
#pragma unroll
      for (int m = 1; m < 16; m <<= 1) {
        s0 += __shfl_xor(s0, m);
        s1 += __shfl_xor(s1, m);
        s2 += __shfl_xor(s2, m);
        s3 += __shfl_xor(s3, m);
      }
      if (fr == 0) {
        int row = row0 + rbase + r;
        *(float4*)(partials + ((size_t)row * NB + chunk) * 4) =
            make_float4(s0, s1, s2, s3);
      }
    }
  }
}

// ---------- D5: reduce partials + ordinal probs ----------
__global__ void probs_k(const float* __restrict__ partials,
                        const int* __restrict__ perm, const int* __restrict__ off,
                        const int* __restrict__ sidx, const float* __restrict__ b2,
                        float* __restrict__ out) {
  int p = blockIdx.x * blockDim.x + threadIdx.x;
  if (p >= off[En]) return;
  int tok = perm[p];
  if (tok < 0) return;
  int e = sidx[tok];
  float s0 = 0.f, s1 = 0.f, s2 = 0.f, s3 = 0.f;
#pragma unroll
  for (int nb = 0; nb < NB; nb++) {
    float4 v = *(const float4*)(partials + ((size_t)p * NB + nb) * 4);
    s0 += v.x; s1 += v.y; s2 += v.z; s3 += v.w;
  }
  float l0 = s0 + b2[e * 4 + 0];
  float l1 = s1 + b2[e * 4 + 1];
  float l2 = s2 + b2[e * 4 + 2];
  float l3 = s3 + b2[e * 4 + 3];
  out[tok * 4 + 0] = l0; out[tok * 4 + 1] = l1;
  out[tok * 4 + 2] = l2; out[tok * 4 + 3] = l3;
  float q0 = 1.f / (1.f + expf(-l0));
  float q1 = 1.f / (1.f + expf(-l1));
  float q2 = 1.f / (1.f + expf(-l2));
  float q3 = 1.f / (1.f + expf(-l3));
  const float eps = 1e-8f;
  float p0 = fmaxf(1.f - q0, eps);
  float p1 = fmaxf(q0 - q1, eps);
  float p2 = fmaxf(q1 - q2, eps);
  float p3 = fmaxf(q2 - q3, eps);
  float p4 = fmaxf(q3, eps);
  float s = p0 + p1 + p2 + p3 + p4;
  float inv = 1.f / fmaxf(s, eps);
  float* pr = out + (size_t)Bn * 4 + (size_t)tok * 5;
  pr[0] = p0 * inv; pr[1] = p1 * inv; pr[2] = p2 * inv;
  pr[3] = p3 * inv; pr[4] = p4 * inv;
}

// ---------- launch ----------
extern "C" void kernel_launch(void* const* d_in, const int* in_sizes, int n_in,
                              void* d_out, int out_size, void* d_ws, size_t ws_size,
                              hipStream_t stream) {
  const float* x  = (const float*)d_in[0];
  const int* sidx = (const int*)d_in[1];
  const float* W1 = (const float*)d_in[2];
  const float* b1 = (const float*)d_in[3];
  const float* W2 = (const float*)d_in[4];
  const float* b2 = (const float*)d_in[5];
  float* out = (float*)d_out;

  uint8_t* w = (uint8_t*)d_ws;
  int* cnt  = (int*)(w + 0);      // 8 ints
  int* gcur = (int*)(w + 32);     // 8 ints
  int* off  = (int*)(w + 64);     // 9 ints
  int* perm = (int*)(w + 512);    // 9216 ints
  u16* xbp     = (u16*)(w + 40960);                    // 18,874,368 B
  u16* w1t     = (u16*)(w + 18915328);                 // 16,777,216 B
  float* parts = (float*)(w + 35692544);               // 2,359,296 B

  hipMemsetAsync(w, 0, 64, stream);                    // cnt + gcur = 0

  prep_k<<<8 + 2048, 256, 0, stream>>>(sidx, W1, w1t, cnt);
  rank_k<<<40, 256, 0, stream>>>(sidx, cnt, gcur, off, perm);
  gather_k<<<PERM_N, 256, 0, stream>>>(x, perm, xbp);
  gemm_k<<<dim3(Hn / 128, MTILES), 256, 0, stream>>>(xbp, w1t, b1, W2, off, parts);
  probs_k<<<(PERM_N + 255) / 256, 256, 0, stream>>>(parts, perm, off, sidx, b2, out);
}

// Round 8
// 155.968 us; speedup vs baseline: 1.4492x; 1.1004x over previous
//
#include <hip/hip_runtime.h>
#include <cstdint>
#include <cstddef>

#define Bn 8192
#define Dn 1024
#define Hn 1024
#define En 8
#define MT 128                     // expert padding quantum / m-tile
#define MTILES (PERM_N / MT)       // 72
#define PERM_N (Bn + En * MT)      // 9216
#define NB 16                      // 64-col partial chunks per row

// prep_k block ranges
#define NXB 4096                   // x-convert blocks
#define NWB 2048                   // W1-transpose blocks
#define XB0 1
#define WB0 (XB0 + NXB)
#define TOTB (WB0 + NWB)           // 6145

typedef unsigned short u16;
typedef __bf16 bf16x8 __attribute__((ext_vector_type(8)));
typedef float f32x4 __attribute__((ext_vector_type(4)));
typedef unsigned short ushort8 __attribute__((ext_vector_type(8)));

// ---------- helpers ----------
__device__ __forceinline__ u16 f2bf(float f) {
  unsigned int u = __float_as_uint(f);
  unsigned int r = u + 0x7fffu + ((u >> 16) & 1u);   // RNE
  return (u16)(r >> 16);
}

__device__ __forceinline__ void gld16(const void* g, void* l) {
  __builtin_amdgcn_global_load_lds(
      (const __attribute__((address_space(1))) void*)g,
      (__attribute__((address_space(3))) void*)l, 16, 0, 0);
}

// wait for own vmcnt<=N (lgkm/exp untouched), then workgroup barrier.
// imm: vmcnt[3:0] | expcnt[6:4] | lgkmcnt[11:8]
#define PIPE_BARRIER_VM4() do {                    \
    asm volatile("" ::: "memory");                 \
    __builtin_amdgcn_s_waitcnt(0x0F74);            \
    __builtin_amdgcn_s_barrier();                  \
    asm volatile("" ::: "memory");                 \
  } while (0)
#define PIPE_BARRIER_VM0() do {                    \
    asm volatile("" ::: "memory");                 \
    __builtin_amdgcn_s_waitcnt(0x0F70);            \
    __builtin_amdgcn_s_barrier();                  \
    asm volatile("" ::: "memory");                 \
  } while (0)

// ---------- D1: routing (block 0) + x->bf16 natural (1..4096) + W1^T (4097..6144) ----
__global__ __launch_bounds__(256) void prep_k(
    const float* __restrict__ x, const int* __restrict__ sidx,
    const float* __restrict__ W1,
    u16* __restrict__ xb, u16* __restrict__ w1t,
    int* __restrict__ off, int* __restrict__ perm) {
  int bid = blockIdx.x;
  int t = threadIdx.x;

  if (bid == 0) {
    // ---- routing (single block, 256 threads, 4 waves) ----
    __shared__ int hist[4][En];
    __shared__ int base[4][En];
    __shared__ int eoff[En + 1];
    int wv = t >> 6;
    if (t < 4 * En) ((int*)hist)[t] = 0;
#pragma unroll
    for (int i = 0; i < PERM_N / 256; i++) perm[t + i * 256] = -1;  // pad fill
    __syncthreads();
    int e32[32], r32[32];
#pragma unroll
    for (int i = 0; i < 32; i++) {
      int e = sidx[t + i * 256];
      e32[i] = e;
      r32[i] = atomicAdd(&hist[wv][e], 1);
    }
    __syncthreads();
    if (t < En) {
      int s = 0;
      for (int w = 0; w < 4; w++) { base[w][t] = s; s += hist[w][t]; }
      hist[0][t] = s;
    }
    __syncthreads();
    if (t == 0) {
      int o = 0;
      for (int e = 0; e < En; e++) {
        eoff[e] = o; off[e] = o;
        o += (hist[0][e] + MT - 1) & ~(MT - 1);
      }
      eoff[En] = o; off[En] = o;
    }
    __syncthreads();
#pragma unroll
    for (int i = 0; i < 32; i++) {
      int e = e32[i];
      perm[eoff[e] + base[wv][e] + r32[i]] = t + i * 256;
    }
  } else if (bid < WB0) {
    // ---- x fp32 -> bf16, natural order (no perm dependency) ----
    size_t idx = ((size_t)(bid - XB0) * 256 + t) * 8;
    const float* src = x + idx;
    float4 a = *(const float4*)src;
    float4 b = *(const float4*)(src + 4);
    ushort8 o;
    o[0] = f2bf(a.x); o[1] = f2bf(a.y); o[2] = f2bf(a.z); o[3] = f2bf(a.w);
    o[4] = f2bf(b.x); o[5] = f2bf(b.y); o[6] = f2bf(b.z); o[7] = f2bf(b.w);
    *(ushort8*)(xb + idx) = o;
  } else {
    // ---- W1 [E][D][H] fp32 -> W1t [E][H][D] bf16, 64x64 LDS transpose ----
    __shared__ float tile[64][65];
    int wb = bid - WB0;
    int e = wb >> 8;
    int k0 = ((wb >> 4) & 15) * 64;   // D
    int n0 = (wb & 15) * 64;          // H
    int c4 = (t & 15) * 4;
    int r0 = t >> 4;                  // 0..15
    const float* src = W1 + ((size_t)e << 20) + (size_t)k0 * Hn + n0;
#pragma unroll
    for (int i = 0; i < 4; i++) {
      int r = r0 + i * 16;
      float4 v = *(const float4*)(src + (size_t)r * Hn + c4);
      tile[r][c4 + 0] = v.x; tile[r][c4 + 1] = v.y;
      tile[r][c4 + 2] = v.z; tile[r][c4 + 3] = v.w;
    }
    __syncthreads();
    u16* dst = w1t + ((size_t)e << 20) + (size_t)n0 * Dn + k0;
#pragma unroll
    for (int i = 0; i < 4; i++) {
      int h = r0 + i * 16;
      ushort4 o;
      o.x = f2bf(tile[c4 + 0][h]);
      o.y = f2bf(tile[c4 + 1][h]);
      o.z = f2bf(tile[c4 + 2][h]);
      o.w = f2bf(tile[c4 + 3][h]);
      *(ushort4*)(dst + (size_t)h * Dn + c4) = o;
    }
  }
}

// ---------- D2: grouped GEMM, 128x128, 3-stage vmcnt(4) pipeline,
// ---------- in-staging A-gather via perm, partials epilogue ----------
__global__ __launch_bounds__(256) void gemm_k(
    const u16* __restrict__ xb, const u16* __restrict__ w1t,
    const float* __restrict__ b1, const float* __restrict__ w2,
    const int* __restrict__ off, const int* __restrict__ perm,
    float* __restrict__ partials) {
  __shared__ u16 As[3][4096];   // 3 stages x 128 rows x 32 k (8 KB each)
  __shared__ u16 Bs[3][4096];

  int n0 = blockIdx.x * 128;            // x = n-tile: pins n-slice to one XCD
  int row0 = blockIdx.y * MT;
  if (row0 >= off[En]) return;          // dead (all-pad) tile
  int e = 0;
  while (row0 >= off[e + 1]) e++;

  int tid = threadIdx.x;
  int lane = tid & 63, w = tid >> 6;
  int wm = w >> 1, wn = w & 1;

  // staging: HW puts lane L at LDS base + L*16B -> (row L>>2, slot L&3).
  // source chunk q = slot ^ swz(row) implements the xor swizzle.
  int srow = lane >> 2;
  int slot = lane & 3;
  int scol = (slot ^ ((srow >> 1) & 3)) * 8;
  const u16* aG[2]; const u16* bG[2];
  int lOff[2];
#pragma unroll
  for (int j = 0; j < 2; j++) {
    int rl = 32 * w + 16 * j + srow;
    int tok = perm[row0 + rl];
    if (tok < 0) tok = 0;               // pad row: any valid row (result discarded)
    aG[j] = xb + ((size_t)tok << 10) + scol;
    bG[j] = w1t + ((size_t)e << 20) + (size_t)(n0 + rl) * Dn + scol;
    lOff[j] = (32 * w + 16 * j) * 32;   // wave-uniform LDS base (elements)
  }

  f32x4 acc[4][4];
#pragma unroll
  for (int i = 0; i < 4; i++)
#pragma unroll
    for (int j = 0; j < 4; j++)
      acc[i][j] = (f32x4){0.f, 0.f, 0.f, 0.f};

  int fr = lane & 15;
  int qf = lane >> 4;
  int qs = (qf ^ ((fr >> 1) & 3)) * 8;
  int offA[4], offB[4];
#pragma unroll
  for (int i = 0; i < 4; i++)
    offA[i] = (wm * 64 + i * 16 + fr) * 32 + qs;
#pragma unroll
  for (int j = 0; j < 4; j++)
    offB[j] = (wn * 64 + j * 16 + fr) * 32 + qs;

  // prologue: stages 0,1 in flight
#pragma unroll
  for (int it = 0; it < 2; it++) {
    int ko = it * 32;
    gld16(aG[0] + ko, (u16*)As[it] + lOff[0]);
    gld16(aG[1] + ko, (u16*)As[it] + lOff[1]);
    gld16(bG[0] + ko, (u16*)Bs[it] + lOff[0]);
    gld16(bG[1] + ko, (u16*)Bs[it] + lOff[1]);
  }

#pragma unroll
  for (int i = 0; i < 31; i++) {
    PIPE_BARRIER_VM4();                 // stage-i loads done; stage-(i+1) in flight
    if (i + 2 < 32) {
      int s = (i + 2) % 3;
      int ko = (i + 2) * 32;
      gld16(aG[0] + ko, (u16*)As[s] + lOff[0]);
      gld16(aG[1] + ko, (u16*)As[s] + lOff[1]);
      gld16(bG[0] + ko, (u16*)Bs[s] + lOff[0]);
      gld16(bG[1] + ko, (u16*)Bs[s] + lOff[1]);
    }
    const u16* Ab = (const u16*)As[i % 3];
    const u16* Bb = (const u16*)Bs[i % 3];
    bf16x8 af[4], bfr[4];
#pragma unroll
    for (int ii = 0; ii < 4; ii++) af[ii] = *(const bf16x8*)(Ab + offA[ii]);
#pragma unroll
    for (int jj = 0; jj < 4; jj++) bfr[jj] = *(const bf16x8*)(Bb + offB[jj]);
#pragma unroll
    for (int ii = 0; ii < 4; ii++)
#pragma unroll
      for (int jj = 0; jj < 4; jj++)
        acc[ii][jj] = __builtin_amdgcn_mfma_f32_16x16x32_bf16(af[ii], bfr[jj], acc[ii][jj], 0, 0, 0);
  }
  {                                     // peeled last iteration (full drain)
    PIPE_BARRIER_VM0();
    const u16* Ab = (const u16*)As[31 % 3];
    const u16* Bb = (const u16*)Bs[31 % 3];
    bf16x8 af[4], bfr[4];
#pragma unroll
    for (int ii = 0; ii < 4; ii++) af[ii] = *(const bf16x8*)(Ab + offA[ii]);
#pragma unroll
    for (int jj = 0; jj < 4; jj++) bfr[jj] = *(const bf16x8*)(Bb + offB[jj]);
#pragma unroll
    for (int ii = 0; ii < 4; ii++)
#pragma unroll
      for (int jj = 0; jj < 4; jj++)
        acc[ii][jj] = __builtin_amdgcn_mfma_f32_16x16x32_bf16(af[ii], bfr[jj], acc[ii][jj], 0, 0, 0);
  }

  // epilogue: h = relu(acc + b1); partial = h . W2[e][col][0..3]; float4 per row/chunk
  int fq = lane >> 4;
  float4 w2v[4]; float b1v[4];
#pragma unroll
  for (int j = 0; j < 4; j++) {
    int col = n0 + wn * 64 + j * 16 + fr;
    w2v[j] = *(const float4*)(w2 + ((size_t)e * Hn + col) * 4);
    b1v[j] = b1[(size_t)e * Hn + col];
  }
  int chunk = blockIdx.x * 2 + wn;      // 64-col chunk 0..15
#pragma unroll
  for (int i = 0; i < 4; i++) {
    int rbase = wm * 64 + i * 16 + fq * 4;
#pragma unroll
    for (int r = 0; r < 4; r++) {
      float s0 = 0.f, s1 = 0.f, s2 = 0.f, s3 = 0.f;
#pragma unroll
      for (int j = 0; j < 4; j++) {
        float h = acc[i][j][r] + b1v[j];
        h = fmaxf(h, 0.f);
        s0 = fmaf(h, w2v[j].x, s0);
        s1 = fmaf(h, w2v[j].y, s1);
        s2 = fmaf(h, w2v[j].z, s2);
        s3 = fmaf(h, w2v[j].w, s3);
      }
#pragma unroll
      for (int m = 1; m < 16; m <<= 1) {
        s0 += __shfl_xor(s0, m);
        s1 += __shfl_xor(s1, m);
        s2 += __shfl_xor(s2, m);
        s3 += __shfl_xor(s3, m);
      }
      if (fr == 0) {
        int row = row0 + rbase + r;
        *(float4*)(partials + ((size_t)row * NB + chunk) * 4) =
            make_float4(s0, s1, s2, s3);
      }
    }
  }
}

// ---------- D3: reduce partials + ordinal probs ----------
__global__ void probs_k(const float* __restrict__ partials,
                        const int* __restrict__ perm, const int* __restrict__ off,
                        const int* __restrict__ sidx, const float* __restrict__ b2,
                        float* __restrict__ out) {
  int p = blockIdx.x * blockDim.x + threadIdx.x;
  if (p >= off[En]) return;
  int tok = perm[p];
  if (tok < 0) return;
  int e = sidx[tok];
  float s0 = 0.f, s1 = 0.f, s2 = 0.f, s3 = 0.f;
#pragma unroll
  for (int nb = 0; nb < NB; nb++) {
    float4 v = *(const float4*)(partials + ((size_t)p * NB + nb) * 4);
    s0 += v.x; s1 += v.y; s2 += v.z; s3 += v.w;
  }
  float l0 = s0 + b2[e * 4 + 0];
  float l1 = s1 + b2[e * 4 + 1];
  float l2 = s2 + b2[e * 4 + 2];
  float l3 = s3 + b2[e * 4 + 3];
  out[tok * 4 + 0] = l0; out[tok * 4 + 1] = l1;
  out[tok * 4 + 2] = l2; out[tok * 4 + 3] = l3;
  float q0 = 1.f / (1.f + expf(-l0));
  float q1 = 1.f / (1.f + expf(-l1));
  float q2 = 1.f / (1.f + expf(-l2));
  float q3 = 1.f / (1.f + expf(-l3));
  const float eps = 1e-8f;
  float p0 = fmaxf(1.f - q0, eps);
  float p1 = fmaxf(q0 - q1, eps);
  float p2 = fmaxf(q1 - q2, eps);
  float p3 = fmaxf(q2 - q3, eps);
  float p4 = fmaxf(q3, eps);
  float s = p0 + p1 + p2 + p3 + p4;
  float inv = 1.f / fmaxf(s, eps);
  float* pr = out + (size_t)Bn * 4 + (size_t)tok * 5;
  pr[0] = p0 * inv; pr[1] = p1 * inv; pr[2] = p2 * inv;
  pr[3] = p3 * inv; pr[4] = p4 * inv;
}

// ---------- launch ----------
extern "C" void kernel_launch(void* const* d_in, const int* in_sizes, int n_in,
                              void* d_out, int out_size, void* d_ws, size_t ws_size,
                              hipStream_t stream) {
  const float* x  = (const float*)d_in[0];
  const int* sidx = (const int*)d_in[1];
  const float* W1 = (const float*)d_in[2];
  const float* b1 = (const float*)d_in[3];
  const float* W2 = (const float*)d_in[4];
  const float* b2 = (const float*)d_in[5];
  float* out = (float*)d_out;

  uint8_t* w = (uint8_t*)d_ws;
  int* off  = (int*)(w + 64);     // 9 ints
  int* perm = (int*)(w + 512);    // 9216 ints
  u16* xb      = (u16*)(w + 40960);                    // 16,777,216 B
  u16* w1t     = (u16*)(w + 40960 + 16777216);         // 16,777,216 B
  float* parts = (float*)(w + 40960 + 2 * 16777216);   // 2,359,296 B

  prep_k<<<TOTB, 256, 0, stream>>>(x, sidx, W1, xb, w1t, off, perm);
  gemm_k<<<dim3(Hn / 128, MTILES), 256, 0, stream>>>(xb, w1t, b1, W2, off, perm, parts);
  probs_k<<<(PERM_N + 255) / 256, 256, 0, stream>>>(parts, perm, off, sidx, b2, out);
}